// Round 2
// baseline (3637.782 us; speedup 1.0000x reference)
//
#include <hip/hip_runtime.h>

// TGN: 2-layer message passing, algebraically refactored:
//  - segment_sum commutes with linear layers -> per-edge GEMM folded into
//    per-node GEMV against precombined weights (make_combos).
//  - edge contribution is layer-invariant -> computed once into ci.
//  - all scatters replaced by dst-CSR gathers (no float atomics).

__global__ __launch_bounds__(256) void node_encode(
    const float* __restrict__ X, const float* __restrict__ Wn,
    const float* __restrict__ bn, float* __restrict__ h, int nNodes) {
  __shared__ float WnT[128][64];  // WnT[k][r] = Wn[r][k]
  int tid = threadIdx.x;
  for (int i = tid; i < 64 * 128; i += 256) {
    int r = i >> 7, c = i & 127;
    WnT[c][r] = Wn[i];
  }
  __syncthreads();
  int lane = tid & 63;
  int wid = blockIdx.x * 4 + (tid >> 6);
  int nw = gridDim.x * 4;
  float bb = bn[lane];
  for (int n = wid; n < nNodes; n += nw) {
    float x0 = X[(size_t)n * 128 + lane];
    float x1 = X[(size_t)n * 128 + 64 + lane];
    float acc = bb;
#pragma unroll
    for (int k = 0; k < 64; ++k) acc += __shfl(x0, k) * WnT[k][lane];
#pragma unroll
    for (int k = 0; k < 64; ++k) acc += __shfl(x1, k) * WnT[64 + k][lane];
    h[(size_t)n * 64 + lane] = fmaxf(acc, 0.f);
  }
}

// ---------- CSR build ----------
__global__ __launch_bounds__(256) void hist_deg(
    const int* __restrict__ dst, int* __restrict__ deg, int nEdges) {
  for (int e = blockIdx.x * 256 + threadIdx.x; e < nEdges; e += gridDim.x * 256)
    atomicAdd(&deg[dst[e]], 1);
}

__global__ __launch_bounds__(1024) void scan_deg(
    const int* __restrict__ deg, int* __restrict__ off, int n) {
  __shared__ int wsum[16];
  __shared__ int carry_s;
  int tid = threadIdx.x;
  int lane = tid & 63, w = tid >> 6;
  if (tid == 0) carry_s = 0;
  __syncthreads();
  for (int base = 0; base < n; base += 1024) {
    int i = base + tid;
    int v = (i < n) ? deg[i] : 0;
    int s = v;  // inclusive wave scan
#pragma unroll
    for (int o = 1; o < 64; o <<= 1) {
      int t = __shfl_up(s, o);
      if (lane >= o) s += t;
    }
    if (lane == 63) wsum[w] = s;
    __syncthreads();
    if (w == 0 && lane < 16) {
      int ws = wsum[lane];
      int ss = ws;
#pragma unroll
      for (int o = 1; o < 16; o <<= 1) {
        int t = __shfl_up(ss, o);
        if (lane >= o) ss += t;
      }
      wsum[lane] = ss - ws;  // exclusive wave offset
    }
    __syncthreads();
    int excl = carry_s + wsum[w] + s - v;
    if (i < n) off[i] = excl;
    __syncthreads();
    if (tid == 1023) carry_s = excl + v;
    __syncthreads();
  }
  if (tid == 0) off[n] = carry_s;
}

__global__ __launch_bounds__(256) void fill_csr(
    const int* __restrict__ src, const int* __restrict__ dst,
    const int* __restrict__ off, int* __restrict__ cursor,
    int* __restrict__ eid, int* __restrict__ srcs, int nEdges) {
  for (int e = blockIdx.x * 256 + threadIdx.x; e < nEdges; e += gridDim.x * 256) {
    int d = dst[e];
    int pos = off[d] + atomicAdd(&cursor[d], 1);
    eid[pos] = e;
    srcs[pos] = src[e];
  }
}

// ---------- edge encoder, CSR-gather form (no atomics) ----------
__global__ __launch_bounds__(256) void edge_encode_csr(
    const float* __restrict__ EA, const float* __restrict__ We,
    const float* __restrict__ be, const int* __restrict__ off,
    const int* __restrict__ eid, float* __restrict__ Esum, int nNodes) {
  __shared__ float WeT[64][64];  // WeT[k][r] = We[r][k]
  int tid = threadIdx.x;
  for (int i = tid; i < 64 * 64; i += 256) {
    int r = i >> 6, c = i & 63;
    WeT[c][r] = We[i];
  }
  __syncthreads();
  int lane = tid & 63;
  int wid = blockIdx.x * 4 + (tid >> 6);
  int nw = gridDim.x * 4;
  float bb = be[lane];
  for (int n = wid; n < nNodes; n += nw) {
    int s0 = off[n], s1 = off[n + 1];
    float accs = 0.f;
    // software-pipeline the next edge's row load under the current GEMV
    float x = 0.f;
    if (s0 < s1) x = EA[(size_t)eid[s0] * 64 + lane];
    for (int idx = s0; idx < s1; ++idx) {
      float xc = x;
      if (idx + 1 < s1) x = EA[(size_t)eid[idx + 1] * 64 + lane];
      float acc = bb;
#pragma unroll
      for (int k = 0; k < 64; ++k) acc += __shfl(xc, k) * WeT[k][lane];
      accs += fmaxf(acc, 0.f);
    }
    Esum[(size_t)n * 64 + lane] = accs;
  }
}

// WchT[k*192+r] = sum_j w_ih[r][j]*W_agg[j][k]; WceT same for e-half;
// bih_agg[r] = sum_j w_ih[r][j]*b_agg[j]
__global__ __launch_bounds__(256) void make_combos(
    const float* __restrict__ wih, const float* __restrict__ Wagg,
    const float* __restrict__ bagg, float* __restrict__ WchT,
    float* __restrict__ WceT, float* __restrict__ bih_agg) {
  int idx = blockIdx.x * 256 + threadIdx.x;
  if (idx < 64 * 192) {
    int k = idx / 192, r = idx % 192;
    float a = 0.f, b = 0.f;
    for (int j = 0; j < 64; ++j) {
      float w = wih[r * 64 + j];
      a += w * Wagg[j * 128 + k];
      b += w * Wagg[j * 128 + 64 + k];
    }
    WchT[k * 192 + r] = a;
    WceT[k * 192 + r] = b;
  }
  if (idx < 192) {
    float s = 0.f;
    for (int j = 0; j < 64; ++j) s += wih[idx * 64 + j] * bagg[j];
    bih_agg[idx] = s;
  }
}

// ci[n][r] = Esum[n] @ WceT + deg[n]*bih_agg[r] + b_ih[r]
__global__ __launch_bounds__(256) void prep_ci(
    const float* __restrict__ Esum, const int* __restrict__ off,
    const float* __restrict__ WceT, const float* __restrict__ bih_agg,
    const float* __restrict__ bih, float* __restrict__ ci, int nNodes) {
  __shared__ float W[64 * 192];
  int tid = threadIdx.x;
  for (int i = tid; i < 64 * 192; i += 256) W[i] = WceT[i];
  __syncthreads();
  int lane = tid & 63;
  int wid = blockIdx.x * 4 + (tid >> 6);
  int nw = gridDim.x * 4;
  float ba0 = bih_agg[lane], ba1 = bih_agg[64 + lane], ba2 = bih_agg[128 + lane];
  float bi0 = bih[lane], bi1 = bih[64 + lane], bi2 = bih[128 + lane];
  for (int n = wid; n < nNodes; n += nw) {
    float x = Esum[(size_t)n * 64 + lane];
    float cn = (float)(off[n + 1] - off[n]);
    float a0 = cn * ba0 + bi0, a1 = cn * ba1 + bi1, a2 = cn * ba2 + bi2;
#pragma unroll
    for (int k = 0; k < 64; ++k) {
      float xb = __shfl(x, k);
      a0 += xb * W[k * 192 + lane];
      a1 += xb * W[k * 192 + 64 + lane];
      a2 += xb * W[k * 192 + 128 + lane];
    }
    ci[(size_t)n * 192 + lane] = a0;
    ci[(size_t)n * 192 + 64 + lane] = a1;
    ci[(size_t)n * 192 + 128 + lane] = a2;
  }
}

// gi[n] = (sum_{e: dst=n} h[src[e]]) @ WchT + ci[n]   (gather fused, no atomics)
__global__ __launch_bounds__(256) void aggregate_gi(
    const float* __restrict__ h, const int* __restrict__ off,
    const int* __restrict__ srcs, const float* __restrict__ WchT,
    const float* __restrict__ ci, float* __restrict__ gi, int nNodes) {
  __shared__ float W[64 * 192];
  int tid = threadIdx.x;
  for (int i = tid; i < 64 * 192; i += 256) W[i] = WchT[i];
  __syncthreads();
  int lane = tid & 63;
  int wid = blockIdx.x * 4 + (tid >> 6);
  int nw = gridDim.x * 4;
  for (int n = wid; n < nNodes; n += nw) {
    int s0 = off[n], s1 = off[n + 1];
    float x = 0.f;
    int idx = s0;
    for (; idx + 4 <= s1; idx += 4) {
      int a = srcs[idx], b = srcs[idx + 1], c = srcs[idx + 2], d = srcs[idx + 3];
      x += h[(size_t)a * 64 + lane];
      x += h[(size_t)b * 64 + lane];
      x += h[(size_t)c * 64 + lane];
      x += h[(size_t)d * 64 + lane];
    }
    for (; idx < s1; ++idx) x += h[(size_t)srcs[idx] * 64 + lane];
    float a0 = ci[(size_t)n * 192 + lane];
    float a1 = ci[(size_t)n * 192 + 64 + lane];
    float a2 = ci[(size_t)n * 192 + 128 + lane];
#pragma unroll
    for (int k = 0; k < 64; ++k) {
      float xb = __shfl(x, k);
      a0 += xb * W[k * 192 + lane];
      a1 += xb * W[k * 192 + 64 + lane];
      a2 += xb * W[k * 192 + 128 + lane];
    }
    gi[(size_t)n * 192 + lane] = a0;
    gi[(size_t)n * 192 + 64 + lane] = a1;
    gi[(size_t)n * 192 + 128 + lane] = a2;
  }
}

__global__ __launch_bounds__(256) void gru_update(
    const float* __restrict__ gi, const float* __restrict__ whh,
    const float* __restrict__ bhh, float* __restrict__ h, int nNodes) {
  __shared__ float W[64 * 192];  // whhT
  int tid = threadIdx.x;
  for (int i = tid; i < 64 * 192; i += 256) {
    int r = i >> 6, k = i & 63;
    W[k * 192 + r] = whh[i];
  }
  __syncthreads();
  int lane = tid & 63;
  int wid = blockIdx.x * 4 + (tid >> 6);
  int nw = gridDim.x * 4;
  float bh0 = bhh[lane], bh1 = bhh[64 + lane], bh2 = bhh[128 + lane];
  for (int n = wid; n < nNodes; n += nw) {
    float hv = h[(size_t)n * 64 + lane];
    float ar = bh0, az = bh1, an = bh2;
#pragma unroll
    for (int k = 0; k < 64; ++k) {
      float hb = __shfl(hv, k);
      ar += hb * W[k * 192 + lane];
      az += hb * W[k * 192 + 64 + lane];
      an += hb * W[k * 192 + 128 + lane];
    }
    float ir = gi[(size_t)n * 192 + lane];
    float iz = gi[(size_t)n * 192 + 64 + lane];
    float in_ = gi[(size_t)n * 192 + 128 + lane];
    float r = 1.f / (1.f + expf(-(ir + ar)));
    float z = 1.f / (1.f + expf(-(iz + az)));
    float nn = tanhf(in_ + r * an);
    h[(size_t)n * 64 + lane] = (1.f - z) * nn + z * hv;
  }
}

__global__ __launch_bounds__(256) void out_mlp(
    const float* __restrict__ h, const int* __restrict__ pm,
    const float* __restrict__ W1, const float* __restrict__ b1,
    const float* __restrict__ W2, const float* __restrict__ b2,
    float* __restrict__ out, int nPosts) {
  int tid = threadIdx.x;
  int lane = tid & 63;
  int p = blockIdx.x * 4 + (tid >> 6);
  if (p >= nPosts) return;
  int n = pm[p];
  float v = h[(size_t)n * 64 + lane];
  int row = lane & 31;
  float o = b1[row];
#pragma unroll
  for (int k = 0; k < 64; ++k) {
    float vb = __shfl(v, k);
    o += vb * W1[row * 64 + k];
  }
  o = fmaxf(o, 0.f);
  float val = o * W2[row] * 0.5f;  // each row computed twice -> halve
#pragma unroll
  for (int offm = 32; offm > 0; offm >>= 1) val += __shfl_xor(val, offm);
  if (lane == 0) out[p] = 1.f / (1.f + expf(-(val + b2[0])));
}

extern "C" void kernel_launch(void* const* d_in, const int* in_sizes, int n_in,
                              void* d_out, int out_size, void* d_ws, size_t ws_size,
                              hipStream_t stream) {
  const float* X    = (const float*)d_in[0];
  const float* EA   = (const float*)d_in[1];
  const int*   EI   = (const int*)d_in[2];
  const int*   PM   = (const int*)d_in[3];
  const float* Wn   = (const float*)d_in[5];
  const float* bn   = (const float*)d_in[6];
  const float* We   = (const float*)d_in[7];
  const float* be   = (const float*)d_in[8];
  const float* Wagg = (const float*)d_in[9];
  const float* bagg = (const float*)d_in[10];
  const float* wih  = (const float*)d_in[11];
  const float* whh  = (const float*)d_in[12];
  const float* bih  = (const float*)d_in[13];
  const float* bhh  = (const float*)d_in[14];
  const float* W1   = (const float*)d_in[15];
  const float* b1   = (const float*)d_in[16];
  const float* W2   = (const float*)d_in[17];
  const float* b2   = (const float*)d_in[18];
  float* out = (float*)d_out;

  int nNodes = in_sizes[0] / 128;
  int nEdges = in_sizes[1] / 64;
  int nPosts = in_sizes[3];
  const int* src = EI;
  const int* dst = EI + nEdges;

  // workspace layout
  char* w = (char*)d_ws;
  float* h    = (float*)w; w += (size_t)nNodes * 64 * 4;
  float* ci   = (float*)w; w += (size_t)nNodes * 192 * 4;
  int*   off  = (int*)w;   w += (size_t)(nNodes + 1) * 4;
  int*   deg  = (int*)w;   w += (size_t)nNodes * 4;
  int*   cur  = (int*)w;   w += (size_t)nNodes * 4;
  int*   eid  = (int*)w;   w += (size_t)nEdges * 4;
  int*   srcs = (int*)w;   w += (size_t)nEdges * 4;
  float* WchT = (float*)w; w += 64 * 192 * 4;
  float* WceT = (float*)w; w += 64 * 192 * 4;
  float* bihA = (float*)w; w += 256 * 4;
  float* gi   = (float*)w;           // nNodes*192*4; Esum aliases (dead after prep_ci)
  float* Esum = gi;

  hipMemsetAsync(deg, 0, (size_t)nNodes * 4, stream);
  hipMemsetAsync(cur, 0, (size_t)nNodes * 4, stream);

  // CSR build (once; reused by 3 gather passes)
  hist_deg<<<2048, 256, 0, stream>>>(dst, deg, nEdges);
  scan_deg<<<1, 1024, 0, stream>>>(deg, off, nNodes);
  fill_csr<<<2048, 256, 0, stream>>>(src, dst, off, cur, eid, srcs, nEdges);

  node_encode<<<1024, 256, 0, stream>>>(X, Wn, bn, h, nNodes);
  edge_encode_csr<<<1024, 256, 0, stream>>>(EA, We, be, off, eid, Esum, nNodes);
  make_combos<<<48, 256, 0, stream>>>(wih, Wagg, bagg, WchT, WceT, bihA);
  prep_ci<<<1024, 256, 0, stream>>>(Esum, off, WceT, bihA, bih, ci, nNodes);

  for (int layer = 0; layer < 2; ++layer) {
    aggregate_gi<<<1024, 256, 0, stream>>>(h, off, srcs, WchT, ci, gi, nNodes);
    gru_update<<<1024, 256, 0, stream>>>(gi, whh, bhh, h, nNodes);
  }

  out_mlp<<<(nPosts + 3) / 4, 256, 0, stream>>>(h, PM, W1, b1, W2, b2, out, nPosts);
}

// Round 3
// 1385.748 us; speedup vs baseline: 2.6251x; 2.6251x over previous
//
#include <hip/hip_runtime.h>

using short8 = __attribute__((ext_vector_type(8))) short;
using f32x4  = __attribute__((ext_vector_type(4))) float;

static __device__ __forceinline__ short f2bf(float f) {
  unsigned u = __float_as_uint(f);
  u += 0x7fffu + ((u >> 16) & 1u);   // RNE to bf16
  return (short)(u >> 16);
}

static __device__ __forceinline__ short8 load8_bf16(const float* __restrict__ p) {
  const f32x4* q = (const f32x4*)p;
  f32x4 a = q[0], b = q[1];
  short8 r;
  r[0] = f2bf(a[0]); r[1] = f2bf(a[1]); r[2] = f2bf(a[2]); r[3] = f2bf(a[3]);
  r[4] = f2bf(b[0]); r[5] = f2bf(b[1]); r[6] = f2bf(b[2]); r[7] = f2bf(b[3]);
  return r;
}

// ---------------- node encoder: h = relu(X @ Wn^T + bn), MFMA ----------------
__global__ __launch_bounds__(256) void node_encode(
    const float* __restrict__ X, const float* __restrict__ Wn,
    const float* __restrict__ bn, float* __restrict__ h, int nNodes) {
  int tid = threadIdx.x;
  int lane = tid & 63, w = tid >> 6, lg = lane >> 4, lr = lane & 15;
  short8 bf[4][4];  // B frag: col=t*16+lr, k=kk*32+lg*8
#pragma unroll
  for (int t = 0; t < 4; ++t)
#pragma unroll
    for (int kk = 0; kk < 4; ++kk)
      bf[t][kk] = load8_bf16(Wn + (t * 16 + lr) * 128 + kk * 32 + lg * 8);
  float bias[4];
#pragma unroll
  for (int t = 0; t < 4; ++t) bias[t] = bn[t * 16 + lr];

  int base = blockIdx.x * 64 + w * 16;
  int arow = base + lr;
  int nn = arow < nNodes ? arow : nNodes - 1;
  f32x4 acc[4] = {};
#pragma unroll
  for (int kk = 0; kk < 4; ++kk) {
    short8 af = load8_bf16(X + (size_t)nn * 128 + kk * 32 + lg * 8);
#pragma unroll
    for (int t = 0; t < 4; ++t)
      acc[t] = __builtin_amdgcn_mfma_f32_16x16x32_bf16(af, bf[t][kk], acc[t], 0, 0, 0);
  }
#pragma unroll
  for (int t = 0; t < 4; ++t)
#pragma unroll
    for (int i = 0; i < 4; ++i) {
      int orow = base + lg * 4 + i;
      if (orow < nNodes)
        h[(size_t)orow * 64 + t * 16 + lr] = fmaxf(acc[t][i] + bias[t], 0.f);
    }
}

// ---------------- CSR build ----------------
__global__ __launch_bounds__(256) void hist_deg(
    const int* __restrict__ dst, int* __restrict__ deg, int nEdges) {
  for (int e = blockIdx.x * 256 + threadIdx.x; e < nEdges; e += gridDim.x * 256)
    atomicAdd(&deg[dst[e]], 1);
}

__global__ __launch_bounds__(1024) void scan_deg(
    const int* __restrict__ deg, int* __restrict__ off, int n) {
  __shared__ int wsum[16];
  __shared__ int carry_s;
  int tid = threadIdx.x;
  int lane = tid & 63, w = tid >> 6;
  if (tid == 0) carry_s = 0;
  __syncthreads();
  for (int base = 0; base < n; base += 1024) {
    int i = base + tid;
    int v = (i < n) ? deg[i] : 0;
    int s = v;
#pragma unroll
    for (int o = 1; o < 64; o <<= 1) {
      int t = __shfl_up(s, o);
      if (lane >= o) s += t;
    }
    if (lane == 63) wsum[w] = s;
    __syncthreads();
    if (w == 0 && lane < 16) {
      int ws = wsum[lane];
      int ss = ws;
#pragma unroll
      for (int o = 1; o < 16; o <<= 1) {
        int t = __shfl_up(ss, o);
        if (lane >= o) ss += t;
      }
      wsum[lane] = ss - ws;
    }
    __syncthreads();
    int excl = carry_s + wsum[w] + s - v;
    if (i < n) off[i] = excl;
    __syncthreads();
    if (tid == 1023) carry_s = excl + v;
    __syncthreads();
  }
  if (tid == 0) off[n] = carry_s;
}

__global__ __launch_bounds__(256) void fill_csr(
    const int* __restrict__ src, const int* __restrict__ dst,
    const int* __restrict__ off, int* __restrict__ cursor,
    int* __restrict__ eid, int* __restrict__ srcs, int nEdges) {
  for (int e = blockIdx.x * 256 + threadIdx.x; e < nEdges; e += gridDim.x * 256) {
    int d = dst[e];
    int pos = off[d] + atomicAdd(&cursor[d], 1);
    eid[pos] = e;
    srcs[pos] = src[e];
  }
}

// per-tile first-node: tnlo[t] = smallest n with off[n+1] > t*64
__global__ __launch_bounds__(256) void tile_nlo_k(
    const int* __restrict__ off, int* __restrict__ tnlo, int nNodes, int nTiles) {
  int t = blockIdx.x * 256 + threadIdx.x;
  if (t > nTiles) return;
  int e0 = t * 64;
  int lo = 0, hi = nNodes - 1;
  while (lo < hi) { int m = (lo + hi) >> 1; if (off[m + 1] > e0) hi = m; else lo = m + 1; }
  tnlo[t] = lo;
}

// ---------------- edge encoder fused with segment-sum (MFMA) ----------------
// Esum[n] = sum_{e: dst=n} relu(EA[e] @ We^T + be); Esum must be pre-zeroed.
__global__ __launch_bounds__(256) void edge_encode_fused(
    const float* __restrict__ EA, const float* __restrict__ We,
    const float* __restrict__ be, const int* __restrict__ off,
    const int* __restrict__ eid, const int* __restrict__ tnlo,
    float* __restrict__ Esum, int nNodes, int nEdges) {
  __shared__ float tile[64][68];
  int tid = threadIdx.x;
  int lane = tid & 63, w = tid >> 6, lg = lane >> 4, lr = lane & 15;

  short8 bf[4][2];
#pragma unroll
  for (int t = 0; t < 4; ++t)
#pragma unroll
    for (int kk = 0; kk < 2; ++kk)
      bf[t][kk] = load8_bf16(We + (t * 16 + lr) * 64 + kk * 32 + lg * 8);
  float bias[4];
#pragma unroll
  for (int t = 0; t < 4; ++t) bias[t] = be[t * 16 + lr];

  int e0 = blockIdx.x * 64;
  int e1 = e0 + 64; if (e1 > nEdges) e1 = nEdges;
  int erow = e0 + w * 16 + lr;
  int eix = eid[erow < nEdges ? erow : nEdges - 1];
  const float* arow = EA + (size_t)eix * 64;
  f32x4 acc[4] = {};
#pragma unroll
  for (int kk = 0; kk < 2; ++kk) {
    short8 af = load8_bf16(arow + kk * 32 + lg * 8);
#pragma unroll
    for (int t = 0; t < 4; ++t)
      acc[t] = __builtin_amdgcn_mfma_f32_16x16x32_bf16(af, bf[t][kk], acc[t], 0, 0, 0);
  }
#pragma unroll
  for (int t = 0; t < 4; ++t)
#pragma unroll
    for (int i = 0; i < 4; ++i)
      tile[w * 16 + lg * 4 + i][t * 16 + lr] = fmaxf(acc[t][i] + bias[t], 0.f);
  __syncthreads();

  int nlo = tnlo[blockIdx.x];
  int nhi = tnlo[blockIdx.x + 1];  // may include trailing zero-contribution nodes (harmless)
  for (int n = nlo + w; n <= nhi; n += 4) {
    int a = off[n], b = off[n + 1];
    int ra = (a > e0 ? a : e0) - e0;
    int rb = (b < e1 ? b : e1) - e0;
    float s = 0.f;
    for (int r = ra; r < rb; ++r) s += tile[r][lane];
    bool interior = (a >= e0) && (b <= e1);
    float* p = &Esum[(size_t)n * 64 + lane];
    if (interior) { if (rb >= ra) *p = s; }
    else if (rb > ra) atomicAdd(p, s);
  }
}

// ---------------- weight combos ----------------
__global__ __launch_bounds__(256) void make_combos(
    const float* __restrict__ wih, const float* __restrict__ Wagg,
    const float* __restrict__ bagg, float* __restrict__ WchT,
    float* __restrict__ WceT, float* __restrict__ bih_agg) {
  int idx = blockIdx.x * 256 + threadIdx.x;
  if (idx < 64 * 192) {
    int k = idx / 192, r = idx % 192;
    float a = 0.f, b = 0.f;
    for (int j = 0; j < 64; ++j) {
      float w = wih[r * 64 + j];
      a += w * Wagg[j * 128 + k];
      b += w * Wagg[j * 128 + 64 + k];
    }
    WchT[k * 192 + r] = a;
    WceT[k * 192 + r] = b;
  }
  if (idx < 192) {
    float s = 0.f;
    for (int j = 0; j < 64; ++j) s += wih[idx * 64 + j] * bagg[j];
    bih_agg[idx] = s;
  }
}

// ---------------- ci = Esum @ WceT + deg*bih_agg + b_ih (4-node ILP) ----------------
__global__ __launch_bounds__(256) void prep_ci(
    const float* __restrict__ Esum, const int* __restrict__ off,
    const float* __restrict__ WceT, const float* __restrict__ bih_agg,
    const float* __restrict__ bih, float* __restrict__ ci, int nNodes) {
  __shared__ float W[64 * 192];
  int tid = threadIdx.x;
  for (int i = tid; i < 64 * 192; i += 256) W[i] = WceT[i];
  __syncthreads();
  int lane = tid & 63;
  int wid = blockIdx.x * 4 + (tid >> 6);
  int nw = gridDim.x * 4;
  float ba0 = bih_agg[lane], ba1 = bih_agg[64 + lane], ba2 = bih_agg[128 + lane];
  float bi0 = bih[lane], bi1 = bih[64 + lane], bi2 = bih[128 + lane];
  for (int n0 = wid * 4; n0 < nNodes; n0 += nw * 4) {
    float x[4], acc[4][3];
#pragma unroll
    for (int j = 0; j < 4; ++j) {
      int n = n0 + j; int nn = n < nNodes ? n : nNodes - 1;
      x[j] = Esum[(size_t)nn * 64 + lane];
      float cn = (float)(off[nn + 1] - off[nn]);
      acc[j][0] = cn * ba0 + bi0; acc[j][1] = cn * ba1 + bi1; acc[j][2] = cn * ba2 + bi2;
    }
#pragma unroll 8
    for (int k = 0; k < 64; ++k) {
      float w0 = W[k * 192 + lane], w1 = W[k * 192 + 64 + lane], w2 = W[k * 192 + 128 + lane];
#pragma unroll
      for (int j = 0; j < 4; ++j) {
        float xb = __shfl(x[j], k);
        acc[j][0] += xb * w0; acc[j][1] += xb * w1; acc[j][2] += xb * w2;
      }
    }
#pragma unroll
    for (int j = 0; j < 4; ++j) {
      int n = n0 + j;
      if (n < nNodes) {
        ci[(size_t)n * 192 + lane] = acc[j][0];
        ci[(size_t)n * 192 + 64 + lane] = acc[j][1];
        ci[(size_t)n * 192 + 128 + lane] = acc[j][2];
      }
    }
  }
}

// ---------------- gi = (sum h[src]) @ WchT + ci (4-node ILP) ----------------
__global__ __launch_bounds__(256) void aggregate_gi(
    const float* __restrict__ h, const int* __restrict__ off,
    const int* __restrict__ srcs, const float* __restrict__ WchT,
    const float* __restrict__ ci, float* __restrict__ gi, int nNodes) {
  __shared__ float W[64 * 192];
  int tid = threadIdx.x;
  for (int i = tid; i < 64 * 192; i += 256) W[i] = WchT[i];
  __syncthreads();
  int lane = tid & 63;
  int wid = blockIdx.x * 4 + (tid >> 6);
  int nw = gridDim.x * 4;
  for (int n0 = wid * 4; n0 < nNodes; n0 += nw * 4) {
    float x[4] = {0.f, 0.f, 0.f, 0.f};
#pragma unroll
    for (int j = 0; j < 4; ++j) {
      int n = n0 + j;
      if (n < nNodes) {
        int s0 = off[n], s1 = off[n + 1];
        int idx = s0;
        for (; idx + 4 <= s1; idx += 4) {
          int a = srcs[idx], b = srcs[idx + 1], c = srcs[idx + 2], d = srcs[idx + 3];
          x[j] += h[(size_t)a * 64 + lane] + h[(size_t)b * 64 + lane] +
                  h[(size_t)c * 64 + lane] + h[(size_t)d * 64 + lane];
        }
        for (; idx < s1; ++idx) x[j] += h[(size_t)srcs[idx] * 64 + lane];
      }
    }
    float acc[4][3];
#pragma unroll
    for (int j = 0; j < 4; ++j) {
      int nn = (n0 + j) < nNodes ? (n0 + j) : nNodes - 1;
      acc[j][0] = ci[(size_t)nn * 192 + lane];
      acc[j][1] = ci[(size_t)nn * 192 + 64 + lane];
      acc[j][2] = ci[(size_t)nn * 192 + 128 + lane];
    }
#pragma unroll 8
    for (int k = 0; k < 64; ++k) {
      float w0 = W[k * 192 + lane], w1 = W[k * 192 + 64 + lane], w2 = W[k * 192 + 128 + lane];
#pragma unroll
      for (int j = 0; j < 4; ++j) {
        float xb = __shfl(x[j], k);
        acc[j][0] += xb * w0; acc[j][1] += xb * w1; acc[j][2] += xb * w2;
      }
    }
#pragma unroll
    for (int j = 0; j < 4; ++j) {
      int n = n0 + j;
      if (n < nNodes) {
        gi[(size_t)n * 192 + lane] = acc[j][0];
        gi[(size_t)n * 192 + 64 + lane] = acc[j][1];
        gi[(size_t)n * 192 + 128 + lane] = acc[j][2];
      }
    }
  }
}

// ---------------- GRU update (4-node ILP) ----------------
__global__ __launch_bounds__(256) void gru_update(
    const float* __restrict__ gi, const float* __restrict__ whh,
    const float* __restrict__ bhh, float* __restrict__ h, int nNodes) {
  __shared__ float W[64 * 192];  // whhT
  int tid = threadIdx.x;
  for (int i = tid; i < 64 * 192; i += 256) {
    int r = i >> 6, k = i & 63;
    W[k * 192 + r] = whh[i];
  }
  __syncthreads();
  int lane = tid & 63;
  int wid = blockIdx.x * 4 + (tid >> 6);
  int nw = gridDim.x * 4;
  float bh0 = bhh[lane], bh1 = bhh[64 + lane], bh2 = bhh[128 + lane];
  for (int n0 = wid * 4; n0 < nNodes; n0 += nw * 4) {
    float hv[4], acc[4][3];
#pragma unroll
    for (int j = 0; j < 4; ++j) {
      int nn = (n0 + j) < nNodes ? (n0 + j) : nNodes - 1;
      hv[j] = h[(size_t)nn * 64 + lane];
      acc[j][0] = bh0; acc[j][1] = bh1; acc[j][2] = bh2;
    }
#pragma unroll 8
    for (int k = 0; k < 64; ++k) {
      float w0 = W[k * 192 + lane], w1 = W[k * 192 + 64 + lane], w2 = W[k * 192 + 128 + lane];
#pragma unroll
      for (int j = 0; j < 4; ++j) {
        float hb = __shfl(hv[j], k);
        acc[j][0] += hb * w0; acc[j][1] += hb * w1; acc[j][2] += hb * w2;
      }
    }
#pragma unroll
    for (int j = 0; j < 4; ++j) {
      int n = n0 + j;
      if (n < nNodes) {
        float ir = gi[(size_t)n * 192 + lane];
        float iz = gi[(size_t)n * 192 + 64 + lane];
        float in_ = gi[(size_t)n * 192 + 128 + lane];
        float r = 1.f / (1.f + expf(-(ir + acc[j][0])));
        float z = 1.f / (1.f + expf(-(iz + acc[j][1])));
        float nn2 = tanhf(in_ + r * acc[j][2]);
        h[(size_t)n * 64 + lane] = (1.f - z) * nn2 + z * hv[j];
      }
    }
  }
}

__global__ __launch_bounds__(256) void out_mlp(
    const float* __restrict__ h, const int* __restrict__ pm,
    const float* __restrict__ W1, const float* __restrict__ b1,
    const float* __restrict__ W2, const float* __restrict__ b2,
    float* __restrict__ out, int nPosts) {
  int tid = threadIdx.x;
  int lane = tid & 63;
  int p = blockIdx.x * 4 + (tid >> 6);
  if (p >= nPosts) return;
  int n = pm[p];
  float v = h[(size_t)n * 64 + lane];
  int row = lane & 31;
  float o = b1[row];
#pragma unroll
  for (int k = 0; k < 64; ++k) {
    float vb = __shfl(v, k);
    o += vb * W1[row * 64 + k];
  }
  o = fmaxf(o, 0.f);
  float val = o * W2[row] * 0.5f;
#pragma unroll
  for (int offm = 32; offm > 0; offm >>= 1) val += __shfl_xor(val, offm);
  if (lane == 0) out[p] = 1.f / (1.f + expf(-(val + b2[0])));
}

extern "C" void kernel_launch(void* const* d_in, const int* in_sizes, int n_in,
                              void* d_out, int out_size, void* d_ws, size_t ws_size,
                              hipStream_t stream) {
  const float* X    = (const float*)d_in[0];
  const float* EA   = (const float*)d_in[1];
  const int*   EI   = (const int*)d_in[2];
  const int*   PM   = (const int*)d_in[3];
  const float* Wn   = (const float*)d_in[5];
  const float* bn   = (const float*)d_in[6];
  const float* We   = (const float*)d_in[7];
  const float* be   = (const float*)d_in[8];
  const float* Wagg = (const float*)d_in[9];
  const float* bagg = (const float*)d_in[10];
  const float* wih  = (const float*)d_in[11];
  const float* whh  = (const float*)d_in[12];
  const float* bih  = (const float*)d_in[13];
  const float* bhh  = (const float*)d_in[14];
  const float* W1   = (const float*)d_in[15];
  const float* b1   = (const float*)d_in[16];
  const float* W2   = (const float*)d_in[17];
  const float* b2   = (const float*)d_in[18];
  float* out = (float*)d_out;

  int nNodes = in_sizes[0] / 128;
  int nEdges = in_sizes[1] / 64;
  int nPosts = in_sizes[3];
  const int* src = EI;
  const int* dst = EI + nEdges;
  int nTiles = (nEdges + 63) / 64;

  // workspace layout
  char* w = (char*)d_ws;
  float* h    = (float*)w; w += (size_t)nNodes * 64 * 4;
  float* ci   = (float*)w; w += (size_t)nNodes * 192 * 4;
  int*   off  = (int*)w;   w += (size_t)(nNodes + 1) * 4;
  int*   deg  = (int*)w;   w += (size_t)nNodes * 4;
  int*   cur  = (int*)w;   w += (size_t)nNodes * 4;
  int*   eid  = (int*)w;   w += (size_t)nEdges * 4;
  int*   srcs = (int*)w;   w += (size_t)nEdges * 4;
  int*   tnlo = (int*)w;   w += (size_t)(nTiles + 1) * 4;
  float* WchT = (float*)w; w += 64 * 192 * 4;
  float* WceT = (float*)w; w += 64 * 192 * 4;
  float* bihA = (float*)w; w += 256 * 4;
  float* gi   = (float*)w;           // nNodes*192*4; Esum aliases (dead after prep_ci)
  float* Esum = gi;

  hipMemsetAsync(deg, 0, (size_t)nNodes * 4, stream);
  hipMemsetAsync(cur, 0, (size_t)nNodes * 4, stream);
  hipMemsetAsync(Esum, 0, (size_t)nNodes * 64 * 4, stream);

  hist_deg<<<2048, 256, 0, stream>>>(dst, deg, nEdges);
  scan_deg<<<1, 1024, 0, stream>>>(deg, off, nNodes);
  fill_csr<<<2048, 256, 0, stream>>>(src, dst, off, cur, eid, srcs, nEdges);
  tile_nlo_k<<<(nTiles + 256) / 256, 256, 0, stream>>>(off, tnlo, nNodes, nTiles);

  node_encode<<<(nNodes + 63) / 64, 256, 0, stream>>>(X, Wn, bn, h, nNodes);
  edge_encode_fused<<<nTiles, 256, 0, stream>>>(EA, We, be, off, eid, tnlo, Esum,
                                                nNodes, nEdges);
  make_combos<<<48, 256, 0, stream>>>(wih, Wagg, bagg, WchT, WceT, bihA);
  prep_ci<<<1024, 256, 0, stream>>>(Esum, off, WceT, bihA, bih, ci, nNodes);

  for (int layer = 0; layer < 2; ++layer) {
    aggregate_gi<<<1024, 256, 0, stream>>>(h, off, srcs, WchT, ci, gi, nNodes);
    gru_update<<<1024, 256, 0, stream>>>(gi, whh, bhh, h, nNodes);
  }

  out_mlp<<<(nPosts + 3) / 4, 256, 0, stream>>>(h, PM, W1, b1, W2, b2, out, nPosts);
}

// Round 4
// 1045.493 us; speedup vs baseline: 3.4795x; 1.3254x over previous
//
#include <hip/hip_runtime.h>

using short8 = __attribute__((ext_vector_type(8))) short;
using f32x4  = __attribute__((ext_vector_type(4))) float;

static __device__ __forceinline__ short f2bf(float f) {
  unsigned u = __float_as_uint(f);
  u += 0x7fffu + ((u >> 16) & 1u);   // RNE to bf16
  return (short)(u >> 16);
}
static __device__ __forceinline__ float bf2f(short s) {
  return __uint_as_float(((unsigned)(unsigned short)s) << 16);
}
static __device__ __forceinline__ short8 load8_bf16(const float* __restrict__ p) {
  const f32x4* q = (const f32x4*)p;
  f32x4 a = q[0], b = q[1];
  short8 r;
  r[0]=f2bf(a[0]); r[1]=f2bf(a[1]); r[2]=f2bf(a[2]); r[3]=f2bf(a[3]);
  r[4]=f2bf(b[0]); r[5]=f2bf(b[1]); r[6]=f2bf(b[2]); r[7]=f2bf(b[3]);
  return r;
}
// hi/lo bf16 split: v ~= hi + lo, 16-bit effective mantissa
static __device__ __forceinline__ void split8(const float* p, short8& hi, short8& lo) {
  const f32x4* q = (const f32x4*)p;
  f32x4 a = q[0], b = q[1];
  float v[8] = {a[0],a[1],a[2],a[3],b[0],b[1],b[2],b[3]};
#pragma unroll
  for (int j = 0; j < 8; ++j) {
    short h = f2bf(v[j]);
    hi[j] = h;
    lo[j] = f2bf(v[j] - bf2f(h));
  }
}

// ---------------- node encoder: h = relu(X @ Wn^T + bn), MFMA, A-split ----------------
__global__ __launch_bounds__(256) void node_encode(
    const float* __restrict__ X, const float* __restrict__ Wn,
    const float* __restrict__ bn, float* __restrict__ h, int nNodes) {
  int tid = threadIdx.x, lane = tid & 63, w = tid >> 6, lg = lane >> 4, lr = lane & 15;
  short8 bf[4][4];
#pragma unroll
  for (int t = 0; t < 4; ++t)
#pragma unroll
    for (int kk = 0; kk < 4; ++kk)
      bf[t][kk] = load8_bf16(Wn + (t*16+lr)*128 + kk*32 + lg*8);
  float bias[4];
#pragma unroll
  for (int t = 0; t < 4; ++t) bias[t] = bn[t*16+lr];

  int base = blockIdx.x * 64 + w * 16;
  int arow = base + lr;
  int nn = arow < nNodes ? arow : nNodes - 1;
  f32x4 acc[4] = {};
#pragma unroll
  for (int kk = 0; kk < 4; ++kk) {
    short8 aH, aL;
    split8(X + (size_t)nn*128 + kk*32 + lg*8, aH, aL);
#pragma unroll
    for (int t = 0; t < 4; ++t) {
      acc[t] = __builtin_amdgcn_mfma_f32_16x16x32_bf16(aH, bf[t][kk], acc[t], 0, 0, 0);
      acc[t] = __builtin_amdgcn_mfma_f32_16x16x32_bf16(aL, bf[t][kk], acc[t], 0, 0, 0);
    }
  }
#pragma unroll
  for (int t = 0; t < 4; ++t)
#pragma unroll
    for (int i = 0; i < 4; ++i) {
      int orow = base + lg*4 + i;
      if (orow < nNodes)
        h[(size_t)orow*64 + t*16 + lr] = fmaxf(acc[t][i] + bias[t], 0.f);
    }
}

// ---------------- CSR build ----------------
__global__ __launch_bounds__(256) void hist_deg(
    const int* __restrict__ dst, int* __restrict__ deg, int nEdges) {
  for (int e = blockIdx.x*256 + threadIdx.x; e < nEdges; e += gridDim.x*256)
    atomicAdd(&deg[dst[e]], 1);
}

// 3-pass scan over deg -> off (4096 elems per block)
__global__ __launch_bounds__(256) void scan_pass1(
    const int* __restrict__ deg, int* __restrict__ bsum, int n) {
  int b = blockIdx.x, tid = threadIdx.x;
  int base = b * 4096;
  int s = 0;
  for (int j = tid; j < 4096; j += 256) {
    int i = base + j;
    s += (i < n) ? deg[i] : 0;
  }
  __shared__ int ws[4];
#pragma unroll
  for (int o = 32; o; o >>= 1) s += __shfl_down(s, o);
  if ((tid & 63) == 0) ws[tid >> 6] = s;
  __syncthreads();
  if (tid == 0) bsum[b] = ws[0] + ws[1] + ws[2] + ws[3];
}

__global__ void scan_pass2(const int* __restrict__ bsum, int* __restrict__ boff,
                           int* __restrict__ off, int nBlocks, int n) {
  if (threadIdx.x == 0 && blockIdx.x == 0) {
    int run = 0;
    for (int b = 0; b < nBlocks; ++b) { boff[b] = run; run += bsum[b]; }
    off[n] = run;
  }
}

__global__ __launch_bounds__(256) void scan_pass3(
    const int* __restrict__ deg, const int* __restrict__ boff,
    int* __restrict__ off, int n) {
  int b = blockIdx.x, tid = threadIdx.x;
  int lane = tid & 63, w = tid >> 6;
  int base = b * 4096 + tid * 16;
  int d[16], tot = 0;
#pragma unroll
  for (int j = 0; j < 16; ++j) {
    d[j] = (base + j < n) ? deg[base + j] : 0;
    tot += d[j];
  }
  int s = tot;
#pragma unroll
  for (int o = 1; o < 64; o <<= 1) {
    int t = __shfl_up(s, o);
    if (lane >= o) s += t;
  }
  __shared__ int ws[4];
  if (lane == 63) ws[w] = s;
  __syncthreads();
  int wo = 0;
  for (int k = 0; k < 4; ++k) wo += (k < w) ? ws[k] : 0;
  int run = boff[b] + wo + s - tot;
#pragma unroll
  for (int j = 0; j < 16; ++j) {
    if (base + j < n) off[base + j] = run;
    run += d[j];
  }
}

__global__ __launch_bounds__(256) void fill_csr(
    const int* __restrict__ src, const int* __restrict__ dst,
    const int* __restrict__ off, int* __restrict__ cursor,
    int* __restrict__ eid, int* __restrict__ srcs, int nEdges) {
  for (int e = blockIdx.x*256 + threadIdx.x; e < nEdges; e += gridDim.x*256) {
    int d = dst[e];
    int pos = off[d] + atomicAdd(&cursor[d], 1);
    eid[pos] = e;
    srcs[pos] = src[e];
  }
}

#define ETILE 128
// tnlo[t] = smallest n with off[n+1] > t*ETILE
__global__ __launch_bounds__(256) void tile_nlo_k(
    const int* __restrict__ off, int* __restrict__ tnlo, int nNodes, int nTiles) {
  int t = blockIdx.x*256 + threadIdx.x;
  if (t > nTiles) return;
  int e0 = t * ETILE;
  int lo = 0, hi = nNodes - 1;
  while (lo < hi) { int m = (lo + hi) >> 1; if (off[m+1] > e0) hi = m; else lo = m + 1; }
  tnlo[t] = lo;
}

// ---------------- edge encoder fused with segment-sum (MFMA, A-split) ----------------
__global__ __launch_bounds__(256) void edge_encode_fused(
    const float* __restrict__ EA, const float* __restrict__ We,
    const float* __restrict__ be, const int* __restrict__ off,
    const int* __restrict__ eid, const int* __restrict__ tnlo,
    float* __restrict__ Esum, int nNodes, int nEdges) {
  __shared__ float tile[ETILE][66];
  int tid = threadIdx.x, lane = tid & 63, w = tid >> 6;
  int lr = lane & 15, lg = lane >> 4;

  short8 bf[4][2];
#pragma unroll
  for (int t = 0; t < 4; ++t)
#pragma unroll
    for (int kk = 0; kk < 2; ++kk)
      bf[t][kk] = load8_bf16(We + (t*16+lr)*64 + kk*32 + lg*8);
  float bias[4];
#pragma unroll
  for (int t = 0; t < 4; ++t) bias[t] = be[t*16+lr];

  int e0 = blockIdx.x * ETILE;
  int e1 = e0 + ETILE; if (e1 > nEdges) e1 = nEdges;
  int er0 = e0 + w*32 + lr;
  int er1 = er0 + 16;
  int ei0 = eid[er0 < nEdges ? er0 : nEdges-1];
  int ei1 = eid[er1 < nEdges ? er1 : nEdges-1];
  const float* r0p = EA + (size_t)ei0*64;
  const float* r1p = EA + (size_t)ei1*64;
  short8 aH[2][2], aL[2][2];
#pragma unroll
  for (int kk = 0; kk < 2; ++kk) {
    split8(r0p + kk*32 + lg*8, aH[0][kk], aL[0][kk]);
    split8(r1p + kk*32 + lg*8, aH[1][kk], aL[1][kk]);
  }
  f32x4 acc[2][4] = {};
#pragma unroll
  for (int b = 0; b < 2; ++b)
#pragma unroll
    for (int kk = 0; kk < 2; ++kk)
#pragma unroll
      for (int t = 0; t < 4; ++t) {
        acc[b][t] = __builtin_amdgcn_mfma_f32_16x16x32_bf16(aH[b][kk], bf[t][kk], acc[b][t], 0,0,0);
        acc[b][t] = __builtin_amdgcn_mfma_f32_16x16x32_bf16(aL[b][kk], bf[t][kk], acc[b][t], 0,0,0);
      }
#pragma unroll
  for (int b = 0; b < 2; ++b)
#pragma unroll
    for (int t = 0; t < 4; ++t)
#pragma unroll
      for (int i = 0; i < 4; ++i)
        tile[w*32 + b*16 + lg*4 + i][t*16 + lr] = fmaxf(acc[b][t][i] + bias[t], 0.f);
  __syncthreads();

  int nlo = tnlo[blockIdx.x], nhi = tnlo[blockIdx.x + 1];
  for (int n = nlo + w; n <= nhi; n += 4) {
    int a = off[n], b2 = off[n+1];
    int ra = (a > e0 ? a : e0) - e0;
    int rb = (b2 < e1 ? b2 : e1) - e0;
    float s = 0.f;
    int r = ra;
    for (; r + 4 <= rb; r += 4)
      s += tile[r][lane] + tile[r+1][lane] + tile[r+2][lane] + tile[r+3][lane];
    for (; r < rb; ++r) s += tile[r][lane];
    bool interior = (a >= e0) && (b2 <= e1);
    float* p = &Esum[(size_t)n*64 + lane];
    if (interior) *p = s;
    else if (rb > ra) atomicAdd(p, s);
  }
}

// ---------------- weight combos (bf16; whh hi/lo split) ----------------
__global__ __launch_bounds__(256) void make_combos(
    const float* __restrict__ wih, const float* __restrict__ Wagg,
    const float* __restrict__ bagg, const float* __restrict__ whh,
    short* __restrict__ WceB, short* __restrict__ WchB,
    short* __restrict__ whhH, short* __restrict__ whhL, float* __restrict__ bihA) {
  int idx = blockIdx.x*256 + threadIdx.x;
  if (idx < 12288) {
    int r = idx >> 6, k = idx & 63;
    float a = 0.f, b = 0.f;
    for (int j = 0; j < 64; ++j) {
      float ww = wih[r*64 + j];
      a += ww * Wagg[j*128 + k];
      b += ww * Wagg[j*128 + 64 + k];
    }
    WchB[idx] = f2bf(a);
    WceB[idx] = f2bf(b);
    float wv = whh[idx];
    short hh = f2bf(wv);
    whhH[idx] = hh;
    whhL[idx] = f2bf(wv - bf2f(hh));
    if (idx < 192) {
      float s = 0.f;
      for (int j = 0; j < 64; ++j) s += wih[idx*64 + j] * bagg[j];
      bihA[idx] = s;
    }
  }
}

// ---------------- fused layer: gather + (Esum@Wce + G@Wch + bias) & h@whh + GRU ----------------
__global__ __launch_bounds__(256) void layer_fused(
    const float* __restrict__ h_old, const float* __restrict__ Esum,
    const int* __restrict__ off, const int* __restrict__ srcs,
    const int* __restrict__ deg,
    const short* __restrict__ WceB, const short* __restrict__ WchB,
    const short* __restrict__ whhH, const short* __restrict__ whhL,
    const float* __restrict__ bihA, const float* __restrict__ bih,
    const float* __restrict__ bhh, float* __restrict__ h_new, int nNodes) {
  __shared__ float G[64][68];
  int tid = threadIdx.x, lane = tid & 63, w = tid >> 6;
  int lr = lane & 15, lg = lane >> 4;
  int nb = blockIdx.x * 64;

  // gather: wave w owns local rows w*16..w*16+15; lane = feature col
  for (int i = 0; i < 16; ++i) {
    int n = nb + w*16 + i;
    float s = 0.f;
    if (n < nNodes) {
      int a = off[n], b = off[n+1], idx = a;
      for (; idx + 4 <= b; idx += 4) {
        int s0 = srcs[idx], s1 = srcs[idx+1], s2 = srcs[idx+2], s3 = srcs[idx+3];
        s += h_old[(size_t)s0*64 + lane] + h_old[(size_t)s1*64 + lane]
           + h_old[(size_t)s2*64 + lane] + h_old[(size_t)s3*64 + lane];
      }
      for (; idx < b; ++idx) s += h_old[(size_t)srcs[idx]*64 + lane];
    }
    G[w*16 + i][lane] = s;
  }
  __syncthreads();

  int arow = nb + w*16 + lr; if (arow >= nNodes) arow = nNodes - 1;
  short8 EsH[2], EsL[2], GHf[2], GLf[2], HH[2], HL[2];
#pragma unroll
  for (int kk = 0; kk < 2; ++kk) {
    split8(Esum + (size_t)arow*64 + kk*32 + lg*8, EsH[kk], EsL[kk]);
    split8(&G[w*16 + lr][kk*32 + lg*8], GHf[kk], GLf[kk]);
    split8(h_old + (size_t)arow*64 + kk*32 + lg*8, HH[kk], HL[kk]);
  }

  int row0 = nb + w*16 + lg*4;
  float degv[4];
#pragma unroll
  for (int i = 0; i < 4; ++i) {
    int n = row0 + i;
    degv[i] = (n < nNodes) ? (float)deg[n] : 0.f;
  }

  f32x4 gi[12], gh[12];
#pragma unroll
  for (int ct = 0; ct < 12; ++ct) {
    float bi = bih[ct*16 + lr], ba = bihA[ct*16 + lr], bh = bhh[ct*16 + lr];
#pragma unroll
    for (int i = 0; i < 4; ++i) { gi[ct][i] = bi + degv[i]*ba; gh[ct][i] = bh; }
  }

#pragma unroll
  for (int ct = 0; ct < 12; ++ct) {
    int wb = (ct*16 + lr)*64 + lg*8;
#pragma unroll
    for (int kk = 0; kk < 2; ++kk) {
      int o = wb + kk*32;
      short8 wce = *(const short8*)(WceB + o);
      short8 wch = *(const short8*)(WchB + o);
      short8 whh_h = *(const short8*)(whhH + o);
      short8 whh_l = *(const short8*)(whhL + o);
      gi[ct] = __builtin_amdgcn_mfma_f32_16x16x32_bf16(EsH[kk], wce, gi[ct], 0,0,0);
      gi[ct] = __builtin_amdgcn_mfma_f32_16x16x32_bf16(EsL[kk], wce, gi[ct], 0,0,0);
      gi[ct] = __builtin_amdgcn_mfma_f32_16x16x32_bf16(GHf[kk], wch, gi[ct], 0,0,0);
      gi[ct] = __builtin_amdgcn_mfma_f32_16x16x32_bf16(GLf[kk], wch, gi[ct], 0,0,0);
      gh[ct] = __builtin_amdgcn_mfma_f32_16x16x32_bf16(HH[kk], whh_h, gh[ct], 0,0,0);
      gh[ct] = __builtin_amdgcn_mfma_f32_16x16x32_bf16(HL[kk], whh_h, gh[ct], 0,0,0);
      gh[ct] = __builtin_amdgcn_mfma_f32_16x16x32_bf16(HH[kk], whh_l, gh[ct], 0,0,0);
    }
  }

  // GRU elementwise: lane holds cols ct*16+lr for rows row0..row0+3
#pragma unroll
  for (int ct = 0; ct < 4; ++ct)
#pragma unroll
    for (int i = 0; i < 4; ++i) {
      int n = row0 + i;
      if (n < nNodes) {
        int jh = ct*16 + lr;
        float r = 1.f/(1.f + expf(-(gi[ct][i] + gh[ct][i])));
        float z = 1.f/(1.f + expf(-(gi[ct+4][i] + gh[ct+4][i])));
        float nn = tanhf(gi[ct+8][i] + r * gh[ct+8][i]);
        float hv = h_old[(size_t)n*64 + jh];
        h_new[(size_t)n*64 + jh] = (1.f - z)*nn + z*hv;
      }
    }
}

__global__ __launch_bounds__(256) void out_mlp(
    const float* __restrict__ h, const int* __restrict__ pm,
    const float* __restrict__ W1, const float* __restrict__ b1,
    const float* __restrict__ W2, const float* __restrict__ b2,
    float* __restrict__ out, int nPosts) {
  int tid = threadIdx.x;
  int lane = tid & 63;
  int p = blockIdx.x*4 + (tid >> 6);
  if (p >= nPosts) return;
  int n = pm[p];
  float v = h[(size_t)n*64 + lane];
  int row = lane & 31;
  float o = b1[row];
#pragma unroll
  for (int k = 0; k < 64; ++k) {
    float vb = __shfl(v, k);
    o += vb * W1[row*64 + k];
  }
  o = fmaxf(o, 0.f);
  float val = o * W2[row] * 0.5f;  // each row computed twice -> halve
#pragma unroll
  for (int offm = 32; offm > 0; offm >>= 1) val += __shfl_xor(val, offm);
  if (lane == 0) out[p] = 1.f/(1.f + expf(-(val + b2[0])));
}

static inline char* aln(char*& w, size_t bytes) {
  uintptr_t p = ((uintptr_t)w + 255) & ~(uintptr_t)255;
  char* r = (char*)p;
  w = r + bytes;
  return r;
}

extern "C" void kernel_launch(void* const* d_in, const int* in_sizes, int n_in,
                              void* d_out, int out_size, void* d_ws, size_t ws_size,
                              hipStream_t stream) {
  const float* X    = (const float*)d_in[0];
  const float* EA   = (const float*)d_in[1];
  const int*   EI   = (const int*)d_in[2];
  const int*   PM   = (const int*)d_in[3];
  const float* Wn   = (const float*)d_in[5];
  const float* bn   = (const float*)d_in[6];
  const float* We   = (const float*)d_in[7];
  const float* be   = (const float*)d_in[8];
  const float* Wagg = (const float*)d_in[9];
  const float* bagg = (const float*)d_in[10];
  const float* wih  = (const float*)d_in[11];
  const float* whh  = (const float*)d_in[12];
  const float* bih  = (const float*)d_in[13];
  const float* bhh  = (const float*)d_in[14];
  const float* W1   = (const float*)d_in[15];
  const float* b1   = (const float*)d_in[16];
  const float* W2   = (const float*)d_in[17];
  const float* b2   = (const float*)d_in[18];
  float* out = (float*)d_out;

  int nNodes = in_sizes[0] / 128;
  int nEdges = in_sizes[1] / 64;
  int nPosts = in_sizes[3];
  const int* src = EI;
  const int* dst = EI + nEdges;
  int nTiles = (nEdges + ETILE - 1) / ETILE;
  int nSB = (nNodes + 4095) / 4096;

  char* w = (char*)d_ws;
  float* h0   = (float*)aln(w, (size_t)nNodes * 64 * 4);
  float* h1   = (float*)aln(w, (size_t)nNodes * 64 * 4);
  float* Esum = (float*)aln(w, (size_t)nNodes * 64 * 4);
  short* WceB = (short*)aln(w, 12288 * 2);
  short* WchB = (short*)aln(w, 12288 * 2);
  short* whhH = (short*)aln(w, 12288 * 2);
  short* whhL = (short*)aln(w, 12288 * 2);
  float* bihA = (float*)aln(w, 192 * 4);
  int*   off  = (int*)aln(w, (size_t)(nNodes + 1) * 4);
  int*   deg  = (int*)aln(w, (size_t)nNodes * 4);
  int*   cur  = (int*)aln(w, (size_t)nNodes * 4);
  int*   eid  = (int*)aln(w, (size_t)nEdges * 4);
  int*   srcs = (int*)aln(w, (size_t)nEdges * 4);
  int*   tnlo = (int*)aln(w, (size_t)(nTiles + 1) * 4);
  int*   bsum = (int*)aln(w, (size_t)nSB * 4);
  int*   boff = (int*)aln(w, (size_t)nSB * 4);

  hipMemsetAsync(deg, 0, (size_t)nNodes * 4, stream);
  hipMemsetAsync(cur, 0, (size_t)nNodes * 4, stream);
  hipMemsetAsync(Esum, 0, (size_t)nNodes * 64 * 4, stream);

  hist_deg<<<2048, 256, 0, stream>>>(dst, deg, nEdges);
  scan_pass1<<<nSB, 256, 0, stream>>>(deg, bsum, nNodes);
  scan_pass2<<<1, 1, 0, stream>>>(bsum, boff, off, nSB, nNodes);
  scan_pass3<<<nSB, 256, 0, stream>>>(deg, boff, off, nNodes);
  fill_csr<<<2048, 256, 0, stream>>>(src, dst, off, cur, eid, srcs, nEdges);
  tile_nlo_k<<<(nTiles + 256) / 256, 256, 0, stream>>>(off, tnlo, nNodes, nTiles);

  node_encode<<<(nNodes + 63) / 64, 256, 0, stream>>>(X, Wn, bn, h0, nNodes);
  edge_encode_fused<<<nTiles, 256, 0, stream>>>(EA, We, be, off, eid, tnlo, Esum,
                                                nNodes, nEdges);
  make_combos<<<48, 256, 0, stream>>>(wih, Wagg, bagg, whh, WceB, WchB, whhH, whhL, bihA);

  layer_fused<<<(nNodes + 63) / 64, 256, 0, stream>>>(
      h0, Esum, off, srcs, deg, WceB, WchB, whhH, whhL, bihA, bih, bhh, h1, nNodes);
  layer_fused<<<(nNodes + 63) / 64, 256, 0, stream>>>(
      h1, Esum, off, srcs, deg, WceB, WchB, whhH, whhL, bihA, bih, bhh, h0, nNodes);

  out_mlp<<<(nPosts + 3) / 4, 256, 0, stream>>>(h0, PM, W1, b1, W2, b2, out, nPosts);
}